// Round 5
// baseline (353.940 us; speedup 1.0000x reference)
//
#include <hip/hip_runtime.h>
#include <cstddef>

#define B_    32
#define N_    1024
#define E_    4096
#define A_    16
#define FIN_  16
#define H_    64
#define MID_  208
#define NODES (B_ * N_)      // 32768
#define NEDGE (B_ * E_)      // 131072
#define ROWS  (B_ * A_ * N_) // 524288
#define AN_   (A_ * N_)      // 16384

__device__ __forceinline__ float readlane_f(float v, int l) {
  return __uint_as_float(__builtin_amdgcn_readlane(__float_as_uint(v), l));
}

// ---------------- CSR build (edges keyed by dst) ----------------
__global__ __launch_bounds__(256) void k_hist(const int* __restrict__ el,
                                              int* __restrict__ counts) {
  int e = blockIdx.x * 256 + threadIdx.x;
  int b = e >> 12;
  int dl = el[b * (2 * E_) + E_ + (e & (E_ - 1))];
  atomicAdd(&counts[b * N_ + dl], 1);
}

// per-graph scan: 32 blocks, each scans 1024 counts; base = b*4096
__global__ __launch_bounds__(256) void k_scan(const int* __restrict__ counts,
                                              int* __restrict__ rowptr,
                                              int* __restrict__ cursor) {
  __shared__ int part[256];
  int b = blockIdx.x, t = threadIdx.x;
  int4 c = *(const int4*)&counts[b * 1024 + t * 4];
  int s = c.x + c.y + c.z + c.w;
  part[t] = s;
  __syncthreads();
  for (int off = 1; off < 256; off <<= 1) {
    int v = (t >= off) ? part[t - off] : 0;
    __syncthreads();
    part[t] += v;
    __syncthreads();
  }
  int prev = ((t == 0) ? 0 : part[t - 1]) + b * E_;
  int p0 = prev, p1 = p0 + c.x, p2 = p1 + c.y, p3 = p2 + c.z;
  int4 r = make_int4(p0, p1, p2, p3);
  *(int4*)&rowptr[b * 1024 + t * 4] = r;
  *(int4*)&cursor[b * 1024 + t * 4] = r;
}

__global__ __launch_bounds__(256) void k_scatter(const int* __restrict__ el,
                                                 int* __restrict__ cursor,
                                                 int* __restrict__ ssrc) {
  int e = blockIdx.x * 256 + threadIdx.x;
  int b = e >> 12;
  int le = e & (E_ - 1);
  int sl = el[b * (2 * E_) + le];
  int dl = el[b * (2 * E_) + E_ + le];
  int pos = atomicAdd(&cursor[b * N_ + dl], 1);
  ssrc[pos] = b * N_ + sl;
}

// ---------------- GIN layer: wave per 4 nodes, register matvec, no LDS ----------------
template <int FINT, bool COPYIN>
__global__ __launch_bounds__(256) void k_layer(const float* __restrict__ xin, int xstride, int in_off,
                                               float* __restrict__ xc, int out_off,
                                               const int* __restrict__ rowptr,
                                               const int* __restrict__ counts,
                                               const int* __restrict__ ssrc,
                                               const float* __restrict__ W,
                                               const float* __restrict__ bias,
                                               const float* __restrict__ g,
                                               const float* __restrict__ beta) {
  int t = threadIdx.x, lane = t & 63, w = t >> 6;
  float Wcol[FINT];
#pragma unroll
  for (int f = 0; f < FINT; f++) Wcol[f] = W[f * 64 + lane];
  float bv = bias[lane], gv = g[lane], bev = beta[lane];
  constexpr int CH = 64 / FINT;
  int f = lane & (FINT - 1);
  int ch = (FINT == 64) ? 0 : (lane >> 4);
  int nbase = (blockIdx.x * 4 + w) * 4;
  for (int nn = 0; nn < 4; nn++) {
    int node = nbase + nn;
    int r0 = rowptr[node];
    int deg = counts[node];
    float aggf = 0.f;
    for (int e = ch; e < deg; e += CH) {
      int s = ssrc[r0 + e];
      aggf += xin[(size_t)s * xstride + in_off + f];
    }
    float y = bv;
#pragma unroll
    for (int l = 0; l < 64; l++) {
      float av = readlane_f(aggf, l);
      y = fmaf(av, Wcol[l & (FINT - 1)], y);
    }
    float m = y;
#pragma unroll
    for (int o = 32; o > 0; o >>= 1) m += __shfl_xor(m, o);
    m *= (1.f / 64.f);
    float d = y - m;
    float vv = d * d;
#pragma unroll
    for (int o = 32; o > 0; o >>= 1) vv += __shfl_xor(vv, o);
    vv *= (1.f / 64.f);
    float outv = fmaxf(d * rsqrtf(vv + 1e-5f) * gv + bev, 0.f);
    xc[(size_t)node * MID_ + out_off + lane] = outv;
    if (COPYIN) {
      if (lane < FIN_) xc[(size_t)node * MID_ + lane] = xin[(size_t)node * FIN_ + lane];
    }
  }
}

// ---------------- pA: 512 agent rows x W1[0:208] ----------------
__global__ __launch_bounds__(256) void k_pA(const float* __restrict__ xc,
                                            const int* __restrict__ loc,
                                            const float* __restrict__ W1,
                                            float* __restrict__ pA) {
  int blk = blockIdx.x;
  int b = blk >> 4;
  __shared__ float xr[MID_];
  int t = threadIdx.x;
  int node = b * N_ + loc[blk];
  if (t < MID_) xr[t] = xc[node * MID_ + t];
  __syncthreads();
  if (t < MID_) {
    float acc = 0.f;
    for (int i = 0; i < MID_; i++) acc = fmaf(xr[i], W1[i * MID_ + t], acc);
    pA[blk * MID_ + t] = acc;
  }
}

// ---------------- cu / base ----------------
__global__ __launch_bounds__(256) void k_cu(const float* __restrict__ W1,
                                            const float* __restrict__ eW,
                                            const float* __restrict__ eb,
                                            const float* __restrict__ b1,
                                            float* __restrict__ cu,
                                            float* __restrict__ base) {
  int j = threadIdx.x;
  if (j < MID_) {
    float c = 0.f, bs = 0.f;
    for (int k = 0; k < H_; k++) {
      float w = W1[(2 * MID_ + k) * MID_ + j];
      c = fmaf(eW[k], w, c);
      bs = fmaf(eb[k], w, bs);
    }
    cu[j] = c;
    base[j] = bs + b1[j];
  }
}

// ---------------- shared GEMM core (r3 LDS-dbuf): 64 rows x 208 j, acc[4][16] ----------------
#define ASTR 72
__device__ __forceinline__ void gemm_core(const float* __restrict__ xc,
                                          const float* __restrict__ W1,
                                          int row0, int t,
                                          float* __restrict__ As,   // [2*16*ASTR]
                                          float* __restrict__ Bs,   // [2*16*256]
                                          float acc[4][16]) {
  int rm = t & 15, rn = t >> 4;
  int arow = t & 63, akq = t >> 6;
#pragma unroll
  for (int i = 0; i < 4; i++)
#pragma unroll
    for (int j = 0; j < 16; j++) acc[i][j] = 0.f;

  float4 aV = *(const float4*)(xc + (size_t)(row0 + arow) * MID_ + akq * 4);
  float bV[16];
#pragma unroll
  for (int i = 0; i < 16; i++) bV[i] = (t < MID_) ? W1[(size_t)(MID_ + i) * MID_ + t] : 0.f;
  As[(akq * 4 + 0) * ASTR + arow] = aV.x;
  As[(akq * 4 + 1) * ASTR + arow] = aV.y;
  As[(akq * 4 + 2) * ASTR + arow] = aV.z;
  As[(akq * 4 + 3) * ASTR + arow] = aV.w;
#pragma unroll
  for (int i = 0; i < 16; i++) Bs[i * 256 + t] = bV[i];
  __syncthreads();

  for (int kt = 0; kt < 13; kt++) {
    int cur = kt & 1;
    float* Asc = As + cur * (16 * ASTR);
    float* Bsc = Bs + cur * (16 * 256);
    float4 aN;
    float bN[16];
    if (kt < 12) {
      int k0 = (kt + 1) * 16;
      aN = *(const float4*)(xc + (size_t)(row0 + arow) * MID_ + k0 + akq * 4);
#pragma unroll
      for (int i = 0; i < 16; i++) bN[i] = (t < MID_) ? W1[(size_t)(MID_ + k0 + i) * MID_ + t] : 0.f;
    }
#pragma unroll 4
    for (int kk = 0; kk < 16; kk++) {
      float4 a4 = *(const float4*)&Asc[kk * ASTR + rm * 4];
      const float* bp = &Bsc[kk * 256 + rn * 16];
      float4 b0 = *(const float4*)(bp);
      float4 b1v = *(const float4*)(bp + 4);
      float4 b2v = *(const float4*)(bp + 8);
      float4 b3v = *(const float4*)(bp + 12);
      float av[4] = {a4.x, a4.y, a4.z, a4.w};
      float bv[16] = {b0.x, b0.y, b0.z, b0.w, b1v.x, b1v.y, b1v.z, b1v.w,
                      b2v.x, b2v.y, b2v.z, b2v.w, b3v.x, b3v.y, b3v.z, b3v.w};
#pragma unroll
      for (int i = 0; i < 4; i++)
#pragma unroll
        for (int j = 0; j < 16; j++) acc[i][j] = fmaf(av[i], bv[j], acc[i][j]);
    }
    __syncthreads();
    if (kt < 12) {
      int nxt = cur ^ 1;
      float* Asn = As + nxt * (16 * ASTR);
      float* Bsn = Bs + nxt * (16 * 256);
      Asn[(akq * 4 + 0) * ASTR + arow] = aN.x;
      Asn[(akq * 4 + 1) * ASTR + arow] = aN.y;
      Asn[(akq * 4 + 2) * ASTR + arow] = aN.z;
      Asn[(akq * 4 + 3) * ASTR + arow] = aN.w;
#pragma unroll
      for (int i = 0; i < 16; i++) Bsn[i * 256 + t] = bN[i];
    }
    __syncthreads();
  }
}

// ---------------- pass1: GEMM + per-block stats partials (no pB materialization) ----------------
__global__ __launch_bounds__(256) void k_pass1(const float* __restrict__ xc,
                                               const float* __restrict__ W1,
                                               const float* __restrict__ e1,
                                               float* __restrict__ SBp) {
  __shared__ float As[2 * 16 * ASTR];
  __shared__ float Bs[2 * 16 * 256];
  int t = threadIdx.x;
  int blk = blockIdx.x;
  int row0 = blk * 64;
  float acc[4][16];
  gemm_core(xc, W1, row0, t, As, Bs, acc);

  int rm = t & 15, rn = t >> 4;
  float4 ev4 = *(const float4*)(e1 + row0 + rm * 4);
  float ev[4] = {ev4.x, ev4.y, ev4.z, ev4.w};
  float* outp = SBp + (size_t)blk * 624;
#pragma unroll
  for (int q = 0; q < 16; q++) {
    float s1 = 0.f, s2 = 0.f, se = 0.f;
#pragma unroll
    for (int i = 0; i < 4; i++) {
      float v = acc[i][q];
      s1 += v;
      s2 = fmaf(v, v, s2);
      se = fmaf(v, ev[i], se);
    }
#pragma unroll
    for (int o = 1; o <= 8; o <<= 1) {
      s1 += __shfl_xor(s1, o);
      s2 += __shfl_xor(s2, o);
      se += __shfl_xor(se, o);
    }
    int j = rn * 16 + q;
    if ((t & 15) == 0 && j < MID_) {
      outp[j] = s1;
      outp[208 + j] = s2;
      outp[416 + j] = se;
    }
  }
}

// ---------------- sbred: fold 16 sub-block partials -> SB[b][3][208] ----------------
__global__ __launch_bounds__(256) void k_sbred(const float* __restrict__ SBp,
                                               float* __restrict__ SB) {
  int b = blockIdx.x, t = threadIdx.x;
  if (t >= MID_) return;
#pragma unroll
  for (int s = 0; s < 3; s++) {
    float a = 0.f;
#pragma unroll 4
    for (int i = 0; i < 16; i++) a += SBp[(size_t)(b * 16 + i) * 624 + s * 208 + t];
    SB[(b * 3 + s) * MID_ + t] = a;
  }
}

// ---------------- dist row sums ----------------
__global__ __launch_bounds__(256) void k_d1(const float* __restrict__ dist,
                                            float* __restrict__ d1row,
                                            float* __restrict__ c2row) {
  int t = threadIdx.x, lane = t & 63, w = t >> 6;
  int r = blockIdx.x * 4 + w;
  const float* dr = dist + (size_t)r * N_;
  float s = 0.f, c2 = 0.f;
#pragma unroll
  for (int k = 0; k < 16; k++) {
    float v = dr[lane + 64 * k];
    s += v;
    c2 = fmaf(v, v, c2);
  }
#pragma unroll
  for (int o = 32; o > 0; o >>= 1) { s += __shfl_xor(s, o); c2 += __shfl_xor(c2, o); }
  if (lane == 0) { d1row[r] = s; c2row[r] = c2; }
}

// ---------------- e1[b][n] = sum_a dist[loc[b,a]][n] ----------------
__global__ __launch_bounds__(256) void k_csum(const float* __restrict__ dist,
                                              const int* __restrict__ loc,
                                              float* __restrict__ e1) {
  __shared__ int loc_s[16];
  int b = blockIdx.x, t = threadIdx.x;
  if (t < 16) loc_s[t] = loc[b * 16 + t];
  __syncthreads();
  float e4[4] = {0.f, 0.f, 0.f, 0.f};
  for (int a = 0; a < 16; a++) {
    const float* dr = dist + (size_t)loc_s[a] * N_;
#pragma unroll
    for (int k = 0; k < 4; k++) e4[k] += dr[t + 256 * k];
  }
#pragma unroll
  for (int k = 0; k < 4; k++) e1[b * N_ + t + 256 * k] = e4[k];
}

// ---------------- BN per-batch partials of the pA terms ----------------
__global__ __launch_bounds__(256) void k_bnpart(const float* __restrict__ pA,
                                                const float* __restrict__ base,
                                                const float* __restrict__ d1row,
                                                const int* __restrict__ loc,
                                                float* __restrict__ Pb) {
  __shared__ float d1s[16];
  int b = blockIdx.x, t = threadIdx.x;
  if (t < 16) d1s[t] = d1row[loc[b * 16 + t]];
  __syncthreads();
  int j = t;
  if (j < MID_) {
    float bj = base[j];
    float t1 = 0.f, t2 = 0.f, t3 = 0.f;
#pragma unroll 4
    for (int a = 0; a < 16; a++) {
      float pa = pA[(b * 16 + a) * MID_ + j] + bj;
      t1 += pa;
      t2 = fmaf(pa, pa, t2);
      t3 = fmaf(pa, d1s[a], t3);
    }
    Pb[(b * 3 + 0) * MID_ + j] = t1;
    Pb[(b * 3 + 1) * MID_ + j] = t2;
    Pb[(b * 3 + 2) * MID_ + j] = t3;
  }
}

// ---------------- BN finalize ----------------
__global__ __launch_bounds__(256) void k_bnfin(const float* __restrict__ Pb,
                                               const float* __restrict__ SB,
                                               const float* __restrict__ cu,
                                               const float* __restrict__ d1row,
                                               const float* __restrict__ c2row,
                                               const int* __restrict__ loc,
                                               const float* __restrict__ bng,
                                               const float* __restrict__ bnb,
                                               const float* __restrict__ W2,
                                               float* __restrict__ scale,
                                               float* __restrict__ shift,
                                               float* __restrict__ wpack4) {
  __shared__ float sred[8];
  int t = threadIdx.x;
  float p1 = 0.f, p2 = 0.f;
  for (int r = t; r < 512; r += 256) {
    int l = loc[r];
    p1 += d1row[l];
    p2 += c2row[l];
  }
#pragma unroll
  for (int o = 32; o > 0; o >>= 1) { p1 += __shfl_xor(p1, o); p2 += __shfl_xor(p2, o); }
  if ((t & 63) == 0) { sred[t >> 6] = p1; sred[4 + (t >> 6)] = p2; }
  __syncthreads();
  float Sc1 = sred[0] + sred[1] + sred[2] + sred[3];
  float Sc2 = sred[4] + sred[5] + sred[6] + sred[7];
  int j = t;
  if (j < MID_) {
    float cuj = cu[j];
    double t1 = 0, t2 = 0, t3 = 0, cross = 0, spb1 = 0, spb2 = 0, spbe = 0;
    for (int b = 0; b < 32; b++) {
      float q1 = Pb[(b * 3 + 0) * MID_ + j];
      float q2 = Pb[(b * 3 + 1) * MID_ + j];
      float q3 = Pb[(b * 3 + 2) * MID_ + j];
      float s1b = SB[(b * 3 + 0) * MID_ + j];
      float s2b = SB[(b * 3 + 1) * MID_ + j];
      float seb = SB[(b * 3 + 2) * MID_ + j];
      t1 += q1; t2 += q2; t3 += q3;
      cross += (double)q1 * s1b;
      spb1 += s1b; spb2 += s2b; spbe += seb;
    }
    double s1 = 1024.0 * t1 + 16.0 * spb1 + (double)cuj * Sc1;
    double s2 = 1024.0 * t2 + 16.0 * spb2 + (double)cuj * cuj * Sc2 +
                2.0 * (cross + (double)cuj * (t3 + spbe));
    double mu = s1 * (1.0 / (double)ROWS);
    double var = s2 * (1.0 / (double)ROWS) - mu * mu;
    float sc = (float)(1.0 / sqrt(var + 1e-5)) * bng[j];
    float sh = bnb[j] - (float)mu * sc;
    scale[j] = sc;
    shift[j] = sh;
    wpack4[4 * j + 0] = sc;
    wpack4[4 * j + 1] = cuj * sc;
    wpack4[4 * j + 2] = W2[j];
    wpack4[4 * j + 3] = 0.f;
  }
}

// ---------------- vaT build ----------------
__global__ __launch_bounds__(256) void k_va(const float* __restrict__ pA,
                                            const float* __restrict__ base,
                                            const float* __restrict__ scale,
                                            const float* __restrict__ shift,
                                            float* __restrict__ vaT) {
  int b = blockIdx.x, j = threadIdx.x;
  if (j >= MID_) return;
  float bj = base[j], sc = scale[j], sh = shift[j];
  float v[16];
#pragma unroll 4
  for (int a = 0; a < 16; a++) {
    float pa = pA[(b * 16 + a) * MID_ + j] + bj;
    v[a] = pa * sc + sh;
  }
  float* dst = vaT + ((size_t)b * MID_ + j) * 16;
#pragma unroll
  for (int q = 0; q < 4; q++)
    *(float4*)(dst + q * 4) = make_float4(v[q * 4], v[q * 4 + 1], v[q * 4 + 2], v[q * 4 + 3]);
}

// ---------------- pass2: GEMM + fused logits (pb via LDS, never global) ----------------
#define ACCS_STR 209
union SMEM2 {
  struct { float As[2 * 16 * ASTR]; float Bs[2 * 16 * 256]; } g;   // 41984 B
  float accS[64 * ACCS_STR];                                       // 53504 B
};
__global__ __launch_bounds__(256) void k_pass2(const float* __restrict__ xc,
                                               const float* __restrict__ W1,
                                               const float* __restrict__ vaT,
                                               const float* __restrict__ wpack4,
                                               const float* __restrict__ dist,
                                               const int* __restrict__ loc,
                                               const int* __restrict__ mask,
                                               const float* __restrict__ b2,
                                               float* __restrict__ lg) {
  __shared__ SMEM2 u;
  __shared__ float accL[4][16][64];
  __shared__ int loc_s[16];
  int t = threadIdx.x, lane = t & 63, w = t >> 6;
  int blk = blockIdx.x;
  int row0 = blk * 64;
  int b = row0 >> 10, n0 = row0 & 1023;
  if (t < 16) loc_s[t] = loc[b * 16 + t];
  float acc[4][16];
  gemm_core(xc, W1, row0, t, u.g.As, u.g.Bs, acc);
  __syncthreads();   // staging buffers dead; safe to alias accS
  int rm = t & 15, rn = t >> 4;
  if (rn < 13) {
#pragma unroll
    for (int i = 0; i < 4; i++) {
      float* dst = &u.accS[(rm * 4 + i) * ACCS_STR + rn * 16];
#pragma unroll
      for (int q = 0; q < 4; q++)
        *(float4*)(dst + q * 4) = make_float4(acc[i][q * 4 + 0], acc[i][q * 4 + 1],
                                              acc[i][q * 4 + 2], acc[i][q * 4 + 3]);
    }
  }
  __syncthreads();

  float c[16];
#pragma unroll
  for (int a = 0; a < 16; a++) c[a] = dist[(size_t)loc_s[a] * N_ + n0 + lane];
  float acc16[16];
#pragma unroll
  for (int a = 0; a < 16; a++) acc16[a] = 0.f;
  const float4* wp = (const float4*)wpack4;
  int j0 = w * 52;
#pragma unroll 4
  for (int jj = 0; jj < 52; jj++) {
    int j = j0 + jj;
    float pbv = u.accS[lane * ACCS_STR + j];
    float4 wv = wp[j];
    float pbs = pbv * wv.x;
    const float* va = vaT + ((size_t)b * MID_ + j) * 16;
#pragma unroll
    for (int a = 0; a < 16; a++) {
      float h = fmaf(c[a], wv.y, va[a] + pbs);
      h = fmaxf(h, 0.f);
      acc16[a] = fmaf(h, wv.z, acc16[a]);
    }
  }
#pragma unroll
  for (int a = 0; a < 16; a++) accL[w][a][lane] = acc16[a];
  __syncthreads();
  float b2v = b2[0];
#pragma unroll
  for (int p = 0; p < 4; p++) {
    int idx = p * 256 + t;
    int a = idx >> 6, nn = idx & 63;
    float s = accL[0][a][nn] + accL[1][a][nn] + accL[2][a][nn] + accL[3][a][nn] + b2v;
    int oi = b * AN_ + a * N_ + n0 + nn;
    lg[oi] = mask[oi] ? s : -1e8f;
  }
}

// ---------------- softmax, 2-phase ----------------
__global__ __launch_bounds__(256) void k_sm1(const float* __restrict__ lg,
                                             float2* __restrict__ P) {
  __shared__ float red[4];
  __shared__ float redS[4];
  int b = blockIdx.y, x = blockIdx.x, t = threadIdx.x;
  const float* lb = lg + b * AN_ + x * 2048;
  float v[8];
  float m = -3.0e38f;
#pragma unroll
  for (int k = 0; k < 8; k++) {
    v[k] = lb[t + 256 * k];
    m = fmaxf(m, v[k]);
  }
#pragma unroll
  for (int o = 32; o > 0; o >>= 1) m = fmaxf(m, __shfl_xor(m, o));
  if ((t & 63) == 0) red[t >> 6] = m;
  __syncthreads();
  m = fmaxf(fmaxf(red[0], red[1]), fmaxf(red[2], red[3]));
  float s = 0.f;
#pragma unroll
  for (int k = 0; k < 8; k++) s += expf(v[k] - m);
#pragma unroll
  for (int o = 32; o > 0; o >>= 1) s += __shfl_xor(s, o);
  if ((t & 63) == 0) redS[t >> 6] = s;
  __syncthreads();
  if (t == 0) P[b * 8 + x] = make_float2(m, redS[0] + redS[1] + redS[2] + redS[3]);
}

__global__ __launch_bounds__(256) void k_sm2(const float* __restrict__ lg,
                                             const float2* __restrict__ P,
                                             float* __restrict__ out) {
  int b = blockIdx.y, x = blockIdx.x, t = threadIdx.x;
  float M = -3.0e38f;
  float2 pr[8];
#pragma unroll
  for (int k = 0; k < 8; k++) {
    pr[k] = P[b * 8 + k];
    M = fmaxf(M, pr[k].x);
  }
  float S = 0.f;
#pragma unroll
  for (int k = 0; k < 8; k++) S += pr[k].y * expf(pr[k].x - M);
  float inv = 1.0f / S;
  const float* lb = lg + b * AN_ + x * 2048;
  float* ob = out + b * AN_ + x * 2048;
#pragma unroll
  for (int k = 0; k < 8; k++) ob[t + 256 * k] = expf(lb[t + 256 * k] - M) * inv;
}

extern "C" void kernel_launch(void* const* d_in, const int* in_sizes, int n_in,
                              void* d_out, int out_size, void* d_ws, size_t ws_size,
                              hipStream_t stream) {
  const float* gn = (const float*)d_in[0];
  const int* el = (const int*)d_in[1];
  const int* loc = (const int*)d_in[2];
  const int* mask = (const int*)d_in[3];
  const float* dist = (const float*)d_in[4];
  const float* c0W = (const float*)d_in[5];
  const float* c0b = (const float*)d_in[6];
  const float* c0g = (const float*)d_in[7];
  const float* c0be = (const float*)d_in[8];
  const float* c1W = (const float*)d_in[9];
  const float* c1b = (const float*)d_in[10];
  const float* c1g = (const float*)d_in[11];
  const float* c1be = (const float*)d_in[12];
  const float* c2W = (const float*)d_in[13];
  const float* c2b = (const float*)d_in[14];
  const float* c2g = (const float*)d_in[15];
  const float* c2be = (const float*)d_in[16];
  const float* eW = (const float*)d_in[17];
  const float* eb = (const float*)d_in[18];
  const float* W1 = (const float*)d_in[19];
  const float* b1 = (const float*)d_in[20];
  const float* bng = (const float*)d_in[21];
  const float* bnb = (const float*)d_in[22];
  const float* W2 = (const float*)d_in[23];
  const float* b2 = (const float*)d_in[24];
  float* out = (float*)d_out;

  char* p = (char*)d_ws;
  auto alloc = [&](size_t bytes) {
    char* r = p;
    p += (bytes + 255) & ~(size_t)255;
    return r;
  };
  int* counts = (int*)alloc((size_t)NODES * 4);
  int* rowptr = (int*)alloc((size_t)NODES * 4);
  int* cursor = (int*)alloc((size_t)NODES * 4);
  int* ssrc = (int*)alloc((size_t)NEDGE * 4);
  float* xc = (float*)alloc((size_t)NODES * MID_ * 4);
  float* pA = (float*)alloc((size_t)512 * MID_ * 4);
  float* cu = (float*)alloc(256 * 4);
  float* base = (float*)alloc(256 * 4);
  float* d1row = (float*)alloc((size_t)N_ * 4);
  float* c2row = (float*)alloc((size_t)N_ * 4);
  float* e1 = (float*)alloc((size_t)B_ * N_ * 4);
  float* SBp = (float*)alloc((size_t)512 * 624 * 4);
  float* SB = (float*)alloc((size_t)B_ * 3 * MID_ * 4);
  float* Pb = (float*)alloc((size_t)B_ * 3 * MID_ * 4);
  float* scale = (float*)alloc(256 * 4);
  float* shift = (float*)alloc(256 * 4);
  float* vaT = (float*)alloc((size_t)B_ * MID_ * 16 * 4);
  float* wpack4 = (float*)alloc((size_t)MID_ * 4 * 4);
  float* lg = (float*)alloc((size_t)ROWS * 4);
  float2* Psm = (float2*)alloc((size_t)256 * 8);

  hipMemsetAsync(counts, 0, (size_t)NODES * 4, stream);

  k_hist<<<512, 256, 0, stream>>>(el, counts);
  k_scan<<<32, 256, 0, stream>>>(counts, rowptr, cursor);
  k_scatter<<<512, 256, 0, stream>>>(el, cursor, ssrc);

  k_layer<16, true><<<2048, 256, 0, stream>>>(gn, FIN_, 0, xc, 16, rowptr, counts, ssrc, c0W, c0b, c0g, c0be);
  k_layer<64, false><<<2048, 256, 0, stream>>>(xc, MID_, 16, xc, 80, rowptr, counts, ssrc, c1W, c1b, c1g, c1be);
  k_layer<64, false><<<2048, 256, 0, stream>>>(xc, MID_, 80, xc, 144, rowptr, counts, ssrc, c2W, c2b, c2g, c2be);

  k_pA<<<512, 256, 0, stream>>>(xc, loc, W1, pA);
  k_cu<<<1, 256, 0, stream>>>(W1, eW, eb, b1, cu, base);
  k_d1<<<256, 256, 0, stream>>>(dist, d1row, c2row);
  k_csum<<<32, 256, 0, stream>>>(dist, loc, e1);

  k_pass1<<<512, 256, 0, stream>>>(xc, W1, e1, SBp);
  k_sbred<<<32, 256, 0, stream>>>(SBp, SB);
  k_bnpart<<<32, 256, 0, stream>>>(pA, base, d1row, loc, Pb);
  k_bnfin<<<1, 256, 0, stream>>>(Pb, SB, cu, d1row, c2row, loc, bng, bnb, W2, scale, shift, wpack4);
  k_va<<<32, 256, 0, stream>>>(pA, base, scale, shift, vaT);

  k_pass2<<<512, 256, 0, stream>>>(xc, W1, vaT, wpack4, dist, loc, mask, b2, lg);
  k_sm1<<<dim3(8, 32), 256, 0, stream>>>(lg, Psm);
  k_sm2<<<dim3(8, 32), 256, 0, stream>>>(lg, Psm, out);
}

// Round 6
// 351.254 us; speedup vs baseline: 1.0076x; 1.0076x over previous
//
#include <hip/hip_runtime.h>
#include <cstddef>

#define B_    32
#define N_    1024
#define E_    4096
#define A_    16
#define FIN_  16
#define H_    64
#define MID_  208
#define NODES (B_ * N_)      // 32768
#define NEDGE (B_ * E_)      // 131072
#define ROWS  (B_ * A_ * N_) // 524288
#define AN_   (A_ * N_)      // 16384

__device__ __forceinline__ float readlane_f(float v, int l) {
  return __uint_as_float(__builtin_amdgcn_readlane(__float_as_uint(v), l));
}

// ---------------- CSR build (edges keyed by dst) ----------------
__global__ __launch_bounds__(256) void k_hist(const int* __restrict__ el,
                                              int* __restrict__ counts) {
  int e = blockIdx.x * 256 + threadIdx.x;
  int b = e >> 12;
  int dl = el[b * (2 * E_) + E_ + (e & (E_ - 1))];
  atomicAdd(&counts[b * N_ + dl], 1);
}

__global__ __launch_bounds__(256) void k_scan(const int* __restrict__ counts,
                                              int* __restrict__ rowptr,
                                              int* __restrict__ cursor) {
  __shared__ int part[256];
  int b = blockIdx.x, t = threadIdx.x;
  int4 c = *(const int4*)&counts[b * 1024 + t * 4];
  int s = c.x + c.y + c.z + c.w;
  part[t] = s;
  __syncthreads();
  for (int off = 1; off < 256; off <<= 1) {
    int v = (t >= off) ? part[t - off] : 0;
    __syncthreads();
    part[t] += v;
    __syncthreads();
  }
  int prev = ((t == 0) ? 0 : part[t - 1]) + b * E_;
  int p0 = prev, p1 = p0 + c.x, p2 = p1 + c.y, p3 = p2 + c.z;
  int4 r = make_int4(p0, p1, p2, p3);
  *(int4*)&rowptr[b * 1024 + t * 4] = r;
  *(int4*)&cursor[b * 1024 + t * 4] = r;
}

__global__ __launch_bounds__(256) void k_scatter(const int* __restrict__ el,
                                                 int* __restrict__ cursor,
                                                 int* __restrict__ ssrc) {
  int e = blockIdx.x * 256 + threadIdx.x;
  int b = e >> 12;
  int le = e & (E_ - 1);
  int sl = el[b * (2 * E_) + le];
  int dl = el[b * (2 * E_) + E_ + le];
  int pos = atomicAdd(&cursor[b * N_ + dl], 1);
  ssrc[pos] = b * N_ + sl;
}

// ---------------- GIN layer: wave per 4 nodes, register matvec, no LDS ----------------
template <int FINT, bool COPYIN>
__global__ __launch_bounds__(256) void k_layer(const float* __restrict__ xin, int xstride, int in_off,
                                               float* __restrict__ xc, int out_off,
                                               const int* __restrict__ rowptr,
                                               const int* __restrict__ counts,
                                               const int* __restrict__ ssrc,
                                               const float* __restrict__ W,
                                               const float* __restrict__ bias,
                                               const float* __restrict__ g,
                                               const float* __restrict__ beta) {
  int t = threadIdx.x, lane = t & 63, w = t >> 6;
  float Wcol[FINT];
#pragma unroll
  for (int f = 0; f < FINT; f++) Wcol[f] = W[f * 64 + lane];
  float bv = bias[lane], gv = g[lane], bev = beta[lane];
  constexpr int CH = 64 / FINT;
  int f = lane & (FINT - 1);
  int ch = (FINT == 64) ? 0 : (lane >> 4);
  int nbase = (blockIdx.x * 4 + w) * 4;
  for (int nn = 0; nn < 4; nn++) {
    int node = nbase + nn;
    int r0 = rowptr[node];
    int deg = counts[node];
    float aggf = 0.f;
    for (int e = ch; e < deg; e += CH) {
      int s = ssrc[r0 + e];
      aggf += xin[(size_t)s * xstride + in_off + f];
    }
    float y = bv;
#pragma unroll
    for (int l = 0; l < 64; l++) {
      float av = readlane_f(aggf, l);
      y = fmaf(av, Wcol[l & (FINT - 1)], y);
    }
    float m = y;
#pragma unroll
    for (int o = 32; o > 0; o >>= 1) m += __shfl_xor(m, o);
    m *= (1.f / 64.f);
    float d = y - m;
    float vv = d * d;
#pragma unroll
    for (int o = 32; o > 0; o >>= 1) vv += __shfl_xor(vv, o);
    vv *= (1.f / 64.f);
    float outv = fmaxf(d * rsqrtf(vv + 1e-5f) * gv + bev, 0.f);
    xc[(size_t)node * MID_ + out_off + lane] = outv;
    if (COPYIN) {
      if (lane < FIN_) xc[(size_t)node * MID_ + lane] = xin[(size_t)node * FIN_ + lane];
    }
  }
}

// ---------------- pA: 512 agent rows x W1[0:208] ----------------
__global__ __launch_bounds__(256) void k_pA(const float* __restrict__ xc,
                                            const int* __restrict__ loc,
                                            const float* __restrict__ W1,
                                            float* __restrict__ pA) {
  int blk = blockIdx.x;
  int b = blk >> 4;
  __shared__ float xr[MID_];
  int t = threadIdx.x;
  int node = b * N_ + loc[blk];
  if (t < MID_) xr[t] = xc[node * MID_ + t];
  __syncthreads();
  if (t < MID_) {
    float acc = 0.f;
    for (int i = 0; i < MID_; i++) acc = fmaf(xr[i], W1[i * MID_ + t], acc);
    pA[blk * MID_ + t] = acc;
  }
}

// ---------------- cu / base ----------------
__global__ __launch_bounds__(256) void k_cu(const float* __restrict__ W1,
                                            const float* __restrict__ eW,
                                            const float* __restrict__ eb,
                                            const float* __restrict__ b1,
                                            float* __restrict__ cu,
                                            float* __restrict__ base) {
  int j = threadIdx.x;
  if (j < MID_) {
    float c = 0.f, bs = 0.f;
    for (int k = 0; k < H_; k++) {
      float w = W1[(2 * MID_ + k) * MID_ + j];
      c = fmaf(eW[k], w, c);
      bs = fmaf(eb[k], w, bs);
    }
    cu[j] = c;
    base[j] = bs + b1[j];
  }
}

// ---------------- LDS-free scalar-A GEMM core: wave = 16 rows, lane = 4 j ----------------
// acc[r][q] = pb[row0w + r][j0 + q]
__device__ __forceinline__ void gemm_sc(const float* __restrict__ xc,
                                        const float* __restrict__ W1,
                                        int row0w, int j0, float acc[16][4]) {
  const float* Bbase = W1 + (size_t)MID_ * MID_;
  const float* Arow = xc + (size_t)row0w * MID_;
#pragma unroll
  for (int r = 0; r < 16; r++)
#pragma unroll
    for (int q = 0; q < 4; q++) acc[r][q] = 0.f;

#pragma unroll 2
  for (int c = 0; c < 52; c++) {
    int k = c * 4;
    float4 a[16];
    const float* ap = Arow + k;
#pragma unroll
    for (int r = 0; r < 16; r++) a[r] = *(const float4*)(ap + r * MID_);
#pragma unroll
    for (int q = 0; q < 4; q++) {
      float4 bq = *(const float4*)(Bbase + (size_t)(k + q) * MID_ + j0);
#pragma unroll
      for (int r = 0; r < 16; r++) {
        float ar = (q == 0) ? a[r].x : (q == 1) ? a[r].y : (q == 2) ? a[r].z : a[r].w;
        acc[r][0] = fmaf(ar, bq.x, acc[r][0]);
        acc[r][1] = fmaf(ar, bq.y, acc[r][1]);
        acc[r][2] = fmaf(ar, bq.z, acc[r][2]);
        acc[r][3] = fmaf(ar, bq.w, acc[r][3]);
      }
    }
  }
}

// ---------------- pass1: GEMM + per-lane stats (no LDS, no barriers) ----------------
// SBp[wave][0:208]=s1, [208:416]=s2, [416:624]=se
__global__ __launch_bounds__(256) void k_pass1(const float* __restrict__ xc,
                                               const float* __restrict__ W1,
                                               const float* __restrict__ e1,
                                               float* __restrict__ SBp) {
  int t = threadIdx.x;
  int lane = t & 63;
  int w = __builtin_amdgcn_readfirstlane(t >> 6);
  int row0w = blockIdx.x * 64 + w * 16;
  int j0 = lane * 4;
  float acc[16][4];
  gemm_sc(xc, W1, row0w, j0, acc);

  // e1 for the wave's 16 rows (wave-uniform -> scalar loads)
  const float* ep = e1 + row0w;
  float4 e0 = *(const float4*)(ep);
  float4 e4 = *(const float4*)(ep + 4);
  float4 e8 = *(const float4*)(ep + 8);
  float4 ec = *(const float4*)(ep + 12);
  float ev[16] = {e0.x, e0.y, e0.z, e0.w, e4.x, e4.y, e4.z, e4.w,
                  e8.x, e8.y, e8.z, e8.w, ec.x, ec.y, ec.z, ec.w};

  if (j0 < MID_) {
    float s1[4] = {0, 0, 0, 0}, s2[4] = {0, 0, 0, 0}, se[4] = {0, 0, 0, 0};
#pragma unroll
    for (int r = 0; r < 16; r++) {
#pragma unroll
      for (int q = 0; q < 4; q++) {
        float v = acc[r][q];
        s1[q] += v;
        s2[q] = fmaf(v, v, s2[q]);
        se[q] = fmaf(v, ev[r], se[q]);
      }
    }
    int wv = blockIdx.x * 4 + w;
    float* o = SBp + (size_t)wv * 624;
    *(float4*)(o + j0) = make_float4(s1[0], s1[1], s1[2], s1[3]);
    *(float4*)(o + 208 + j0) = make_float4(s2[0], s2[1], s2[2], s2[3]);
    *(float4*)(o + 416 + j0) = make_float4(se[0], se[1], se[2], se[3]);
  }
}

// ---------------- sbpart: fold 64 wave-partials -> SB[b][3][208]; + pA partials -> Pb ----------------
__global__ __launch_bounds__(256) void k_sbpart(const float* __restrict__ SBp,
                                                const float* __restrict__ pA,
                                                const float* __restrict__ base,
                                                const float* __restrict__ d1row,
                                                const int* __restrict__ loc,
                                                float* __restrict__ SB,
                                                float* __restrict__ Pb) {
  __shared__ float d1s[16];
  int b = blockIdx.x, t = threadIdx.x;
  if (t < 16) d1s[t] = d1row[loc[b * 16 + t]];
  __syncthreads();
  int j = t;
  if (j >= MID_) return;
  float s0 = 0.f, s1 = 0.f, s2 = 0.f;
  const float* src = SBp + (size_t)b * 64 * 624;
#pragma unroll 4
  for (int i = 0; i < 64; i++) {
    s0 += src[i * 624 + j];
    s1 += src[i * 624 + 208 + j];
    s2 += src[i * 624 + 416 + j];
  }
  SB[(b * 3 + 0) * MID_ + j] = s0;
  SB[(b * 3 + 1) * MID_ + j] = s1;
  SB[(b * 3 + 2) * MID_ + j] = s2;

  float bj = base[j];
  float t1 = 0.f, t2 = 0.f, t3 = 0.f;
#pragma unroll 4
  for (int a = 0; a < 16; a++) {
    float pa = pA[(b * 16 + a) * MID_ + j] + bj;
    t1 += pa;
    t2 = fmaf(pa, pa, t2);
    t3 = fmaf(pa, d1s[a], t3);
  }
  Pb[(b * 3 + 0) * MID_ + j] = t1;
  Pb[(b * 3 + 1) * MID_ + j] = t2;
  Pb[(b * 3 + 2) * MID_ + j] = t3;
}

// ---------------- dist row sums ----------------
__global__ __launch_bounds__(256) void k_d1(const float* __restrict__ dist,
                                            float* __restrict__ d1row,
                                            float* __restrict__ c2row) {
  int t = threadIdx.x, lane = t & 63, w = t >> 6;
  int r = blockIdx.x * 4 + w;
  const float* dr = dist + (size_t)r * N_;
  float s = 0.f, c2 = 0.f;
#pragma unroll
  for (int k = 0; k < 16; k++) {
    float v = dr[lane + 64 * k];
    s += v;
    c2 = fmaf(v, v, c2);
  }
#pragma unroll
  for (int o = 32; o > 0; o >>= 1) { s += __shfl_xor(s, o); c2 += __shfl_xor(c2, o); }
  if (lane == 0) { d1row[r] = s; c2row[r] = c2; }
}

// ---------------- e1[b][n] = sum_a dist[loc[b,a]][n] ----------------
__global__ __launch_bounds__(256) void k_csum(const float* __restrict__ dist,
                                              const int* __restrict__ loc,
                                              float* __restrict__ e1) {
  __shared__ int loc_s[16];
  int b = blockIdx.x, t = threadIdx.x;
  if (t < 16) loc_s[t] = loc[b * 16 + t];
  __syncthreads();
  float e4[4] = {0.f, 0.f, 0.f, 0.f};
  for (int a = 0; a < 16; a++) {
    const float* dr = dist + (size_t)loc_s[a] * N_;
#pragma unroll
    for (int k = 0; k < 4; k++) e4[k] += dr[t + 256 * k];
  }
#pragma unroll
  for (int k = 0; k < 4; k++) e1[b * N_ + t + 256 * k] = e4[k];
}

// ---------------- finva: BN finalize (redundant per block) + vaT for own b ----------------
__global__ __launch_bounds__(256) void k_finva(const float* __restrict__ Pb,
                                               const float* __restrict__ SB,
                                               const float* __restrict__ cu,
                                               const float* __restrict__ base,
                                               const float* __restrict__ d1row,
                                               const float* __restrict__ c2row,
                                               const int* __restrict__ loc,
                                               const float* __restrict__ bng,
                                               const float* __restrict__ bnb,
                                               const float* __restrict__ W2,
                                               const float* __restrict__ pA,
                                               float* __restrict__ vaT,
                                               float* __restrict__ wpack4) {
  __shared__ float sred[8];
  int t = threadIdx.x;
  float p1 = 0.f, p2 = 0.f;
  for (int r = t; r < 512; r += 256) {
    int l = loc[r];
    p1 += d1row[l];
    p2 += c2row[l];
  }
#pragma unroll
  for (int o = 32; o > 0; o >>= 1) { p1 += __shfl_xor(p1, o); p2 += __shfl_xor(p2, o); }
  if ((t & 63) == 0) { sred[t >> 6] = p1; sred[4 + (t >> 6)] = p2; }
  __syncthreads();
  float Sc1 = sred[0] + sred[1] + sred[2] + sred[3];
  float Sc2 = sred[4] + sred[5] + sred[6] + sred[7];
  int j = t;
  if (j >= MID_) return;
  float cuj = cu[j];
  double t1 = 0, t2 = 0, t3 = 0, cross = 0, spb1 = 0, spb2 = 0, spbe = 0;
  for (int b = 0; b < 32; b++) {
    float q1 = Pb[(b * 3 + 0) * MID_ + j];
    float q2 = Pb[(b * 3 + 1) * MID_ + j];
    float q3 = Pb[(b * 3 + 2) * MID_ + j];
    float s1b = SB[(b * 3 + 0) * MID_ + j];
    float s2b = SB[(b * 3 + 1) * MID_ + j];
    float seb = SB[(b * 3 + 2) * MID_ + j];
    t1 += q1; t2 += q2; t3 += q3;
    cross += (double)q1 * s1b;
    spb1 += s1b; spb2 += s2b; spbe += seb;
  }
  double s1 = 1024.0 * t1 + 16.0 * spb1 + (double)cuj * Sc1;
  double s2 = 1024.0 * t2 + 16.0 * spb2 + (double)cuj * cuj * Sc2 +
              2.0 * (cross + (double)cuj * (t3 + spbe));
  double mu = s1 * (1.0 / (double)ROWS);
  double var = s2 * (1.0 / (double)ROWS) - mu * mu;
  float sc = (float)(1.0 / sqrt(var + 1e-5)) * bng[j];
  float sh = bnb[j] - (float)mu * sc;
  int b = blockIdx.x;
  if (b == 0) {
    wpack4[4 * j + 0] = sc;
    wpack4[4 * j + 1] = cuj * sc;
    wpack4[4 * j + 2] = W2[j];
    wpack4[4 * j + 3] = 0.f;
  }
  float bj = base[j];
  float v[16];
#pragma unroll 4
  for (int a = 0; a < 16; a++) {
    float pa = pA[(b * 16 + a) * MID_ + j] + bj;
    v[a] = pa * sc + sh;
  }
  float* dst = vaT + ((size_t)b * MID_ + j) * 16;
#pragma unroll
  for (int q = 0; q < 4; q++)
    *(float4*)(dst + q * 4) = make_float4(v[q * 4], v[q * 4 + 1], v[q * 4 + 2], v[q * 4 + 3]);
}

// ---------------- pass2: scalar-A GEMM + accS transpose + logits + softmax partials ----------------
#define ACCS_STR 209
__global__ __launch_bounds__(256) void k_pass2(const float* __restrict__ xc,
                                               const float* __restrict__ W1,
                                               const float* __restrict__ vaT,
                                               const float* __restrict__ wpack4,
                                               const float* __restrict__ dist,
                                               const int* __restrict__ loc,
                                               const int* __restrict__ mask,
                                               const float* __restrict__ b2,
                                               float* __restrict__ lg,
                                               float2* __restrict__ Psm) {
  __shared__ float accS[64 * ACCS_STR];   // 53504 B
  __shared__ float accL[4][8][64];        // 8192 B
  __shared__ int loc_s[16];
  __shared__ float redm[4];
  __shared__ float reds[4];
  int t = threadIdx.x, lane = t & 63;
  int w = __builtin_amdgcn_readfirstlane(t >> 6);
  int blk = blockIdx.x;
  int row0 = blk * 64;
  int b = blk >> 4, n0 = (blk & 15) * 64;
  if (t < 16) loc_s[t] = loc[b * 16 + t];
  int row0w = row0 + w * 16;
  int j0 = lane * 4;
  float acc[16][4];
  gemm_sc(xc, W1, row0w, j0, acc);
  if (j0 < MID_) {
#pragma unroll
    for (int r = 0; r < 16; r++) {
      int ba = (w * 16 + r) * ACCS_STR + j0;
      accS[ba + 0] = acc[r][0];
      accS[ba + 1] = acc[r][1];
      accS[ba + 2] = acc[r][2];
      accS[ba + 3] = acc[r][3];
    }
  }
  __syncthreads();

  float c[16];
#pragma unroll
  for (int a = 0; a < 16; a++) c[a] = dist[(size_t)loc_s[a] * N_ + n0 + lane];
  float acc16[16];
#pragma unroll
  for (int a = 0; a < 16; a++) acc16[a] = 0.f;
  const float4* wp = (const float4*)wpack4;
  int jb = w * 52;
#pragma unroll 4
  for (int jj = 0; jj < 52; jj++) {
    int j = jb + jj;
    float pbv = accS[lane * ACCS_STR + j];
    float4 wv = wp[j];
    float pbs = pbv * wv.x;
    const float* va = vaT + ((size_t)b * MID_ + j) * 16;
#pragma unroll
    for (int a = 0; a < 16; a++) {
      float h = fmaf(c[a], wv.y, va[a] + pbs);
      h = fmaxf(h, 0.f);
      acc16[a] = fmaf(h, wv.z, acc16[a]);
    }
  }

  float b2v = b2[0];
  float sv[4];
  int ois[4];
  unsigned mk = 0;
#pragma unroll
  for (int half = 0; half < 2; half++) {
#pragma unroll
    for (int a8 = 0; a8 < 8; a8++) accL[t >> 6][a8][lane] = acc16[half * 8 + a8];
    __syncthreads();
#pragma unroll
    for (int p = 0; p < 2; p++) {
      int idx = p * 256 + t;
      int a8 = idx >> 6, nn = idx & 63;
      float s = accL[0][a8][nn] + accL[1][a8][nn] + accL[2][a8][nn] + accL[3][a8][nn] + b2v;
      int a = half * 8 + a8;
      int oi = b * AN_ + a * N_ + n0 + nn;
      int iv = half * 2 + p;
      bool m_ = mask[oi] != 0;
      sv[iv] = m_ ? s : -1e8f;
      ois[iv] = oi;
      mk |= (m_ ? 1u : 0u) << iv;
    }
    __syncthreads();
  }

  // block max
  float mx = fmaxf(fmaxf(sv[0], sv[1]), fmaxf(sv[2], sv[3]));
#pragma unroll
  for (int o = 32; o > 0; o >>= 1) mx = fmaxf(mx, __shfl_xor(mx, o));
  if (lane == 0) redm[t >> 6] = mx;
  __syncthreads();
  mx = fmaxf(fmaxf(redm[0], redm[1]), fmaxf(redm[2], redm[3]));
  // exp + sum + store
  float ssum = 0.f;
#pragma unroll
  for (int iv = 0; iv < 4; iv++) {
    float pv = ((mk >> iv) & 1u) ? expf(sv[iv] - mx) : 0.f;
    lg[ois[iv]] = pv;
    ssum += pv;
  }
#pragma unroll
  for (int o = 32; o > 0; o >>= 1) ssum += __shfl_xor(ssum, o);
  if (lane == 0) reds[t >> 6] = ssum;
  __syncthreads();
  if (t == 0) Psm[b * 16 + (blk & 15)] = make_float2(mx, reds[0] + reds[1] + reds[2] + reds[3]);
}

// ---------------- sm2: combine 16 block-partials per batch, normalize ----------------
__global__ __launch_bounds__(256) void k_sm2(const float* __restrict__ lg,
                                             const float2* __restrict__ P,
                                             float* __restrict__ out) {
  __shared__ float scs[16];
  int b = blockIdx.y, x = blockIdx.x, t = threadIdx.x;
  float M = -3.0e38f;
  float2 pr[16];
#pragma unroll
  for (int k = 0; k < 16; k++) {
    pr[k] = P[b * 16 + k];
    M = fmaxf(M, pr[k].x);
  }
  float S = 0.f;
#pragma unroll
  for (int k = 0; k < 16; k++) S += pr[k].y * expf(pr[k].x - M);
  float inv = 1.0f / S;
  if (t < 16) scs[t] = expf(pr[t].x - M) * inv;
  __syncthreads();
  const float* lb = lg + b * AN_ + x * 2048;
  float* ob = out + b * AN_ + x * 2048;
#pragma unroll
  for (int k = 0; k < 8; k++) {
    int i = t + 256 * k;
    int n = (x * 2048 + i) & 1023;
    ob[i] = lb[i] * scs[n >> 6];
  }
}

extern "C" void kernel_launch(void* const* d_in, const int* in_sizes, int n_in,
                              void* d_out, int out_size, void* d_ws, size_t ws_size,
                              hipStream_t stream) {
  const float* gn = (const float*)d_in[0];
  const int* el = (const int*)d_in[1];
  const int* loc = (const int*)d_in[2];
  const int* mask = (const int*)d_in[3];
  const float* dist = (const float*)d_in[4];
  const float* c0W = (const float*)d_in[5];
  const float* c0b = (const float*)d_in[6];
  const float* c0g = (const float*)d_in[7];
  const float* c0be = (const float*)d_in[8];
  const float* c1W = (const float*)d_in[9];
  const float* c1b = (const float*)d_in[10];
  const float* c1g = (const float*)d_in[11];
  const float* c1be = (const float*)d_in[12];
  const float* c2W = (const float*)d_in[13];
  const float* c2b = (const float*)d_in[14];
  const float* c2g = (const float*)d_in[15];
  const float* c2be = (const float*)d_in[16];
  const float* eW = (const float*)d_in[17];
  const float* eb = (const float*)d_in[18];
  const float* W1 = (const float*)d_in[19];
  const float* b1 = (const float*)d_in[20];
  const float* bng = (const float*)d_in[21];
  const float* bnb = (const float*)d_in[22];
  const float* W2 = (const float*)d_in[23];
  const float* b2 = (const float*)d_in[24];
  float* out = (float*)d_out;

  char* p = (char*)d_ws;
  auto alloc = [&](size_t bytes) {
    char* r = p;
    p += (bytes + 255) & ~(size_t)255;
    return r;
  };
  int* counts = (int*)alloc((size_t)NODES * 4);
  int* rowptr = (int*)alloc((size_t)NODES * 4);
  int* cursor = (int*)alloc((size_t)NODES * 4);
  int* ssrc = (int*)alloc((size_t)NEDGE * 4);
  float* xc = (float*)alloc((size_t)NODES * MID_ * 4);
  float* pA = (float*)alloc((size_t)512 * MID_ * 4);
  float* cu = (float*)alloc(256 * 4);
  float* base = (float*)alloc(256 * 4);
  float* d1row = (float*)alloc((size_t)N_ * 4);
  float* c2row = (float*)alloc((size_t)N_ * 4);
  float* e1 = (float*)alloc((size_t)B_ * N_ * 4);
  float* SBp = (float*)alloc((size_t)2048 * 624 * 4);
  float* SB = (float*)alloc((size_t)B_ * 3 * MID_ * 4);
  float* Pb = (float*)alloc((size_t)B_ * 3 * MID_ * 4);
  float* vaT = (float*)alloc((size_t)B_ * MID_ * 16 * 4);
  float* wpack4 = (float*)alloc((size_t)MID_ * 4 * 4);
  float* lg = (float*)alloc((size_t)ROWS * 4);
  float2* Psm = (float2*)alloc((size_t)B_ * 16 * 8);

  hipMemsetAsync(counts, 0, (size_t)NODES * 4, stream);

  k_hist<<<512, 256, 0, stream>>>(el, counts);
  k_scan<<<32, 256, 0, stream>>>(counts, rowptr, cursor);
  k_scatter<<<512, 256, 0, stream>>>(el, cursor, ssrc);

  k_layer<16, true><<<2048, 256, 0, stream>>>(gn, FIN_, 0, xc, 16, rowptr, counts, ssrc, c0W, c0b, c0g, c0be);
  k_layer<64, false><<<2048, 256, 0, stream>>>(xc, MID_, 16, xc, 80, rowptr, counts, ssrc, c1W, c1b, c1g, c1be);
  k_layer<64, false><<<2048, 256, 0, stream>>>(xc, MID_, 80, xc, 144, rowptr, counts, ssrc, c2W, c2b, c2g, c2be);

  k_pA<<<512, 256, 0, stream>>>(xc, loc, W1, pA);
  k_cu<<<1, 256, 0, stream>>>(W1, eW, eb, b1, cu, base);
  k_d1<<<256, 256, 0, stream>>>(dist, d1row, c2row);
  k_csum<<<32, 256, 0, stream>>>(dist, loc, e1);

  k_pass1<<<512, 256, 0, stream>>>(xc, W1, e1, SBp);
  k_sbpart<<<32, 256, 0, stream>>>(SBp, pA, base, d1row, loc, SB, Pb);
  k_finva<<<32, 256, 0, stream>>>(Pb, SB, cu, base, d1row, c2row, loc, bng, bnb, W2, pA, vaT, wpack4);

  k_pass2<<<512, 256, 0, stream>>>(xc, W1, vaT, wpack4, dist, loc, mask, b2, lg, Psm);
  k_sm2<<<dim3(8, 32), 256, 0, stream>>>(lg, Psm, out);
}